// Round 3
// baseline (3870.795 us; speedup 1.0000x reference)
//
#include <hip/hip_runtime.h>
#include <hip/hip_bf16.h>

typedef __hip_bfloat16 bf16;

#define B_      2
#define T_      2048
#define C_      2048
#define H_      16
#define HD_     128
#define NT_     (B_ * T_)
#define DOWN_N  1088
#define KV_N    3072
#define Q_N     2048
#define G_N     80
#define EPS_    1.1920929e-07f

__device__ __forceinline__ float tof(bf16 v) { return __bfloat162float(v); }
__device__ __forceinline__ float tof(float v) { return v; }

template <typename T> __device__ __forceinline__ T fromf(float v);
template <> __device__ __forceinline__ float fromf<float>(float v) { return v; }
template <> __device__ __forceinline__ bf16 fromf<bf16>(float v) { return __float2bfloat16(v); }

// Runtime-dtype load: bf==0 -> f32, bf==1 -> bf16 (element index i either way).
__device__ __forceinline__ float dynload(const void* p, size_t i, int bf) {
    if (bf) {
        unsigned u = ((const unsigned short*)p)[i];
        union { unsigned u; float f; } c; c.u = u << 16;
        return c.f;
    }
    return ((const float*)p)[i];
}

// ---------------------------------------------------------------------------
// Input dtype detector: examine low half-words of x. bf16 data -> both halves
// are valid bf16 (exp in-range ~100%); f32 data -> low half is mantissa bits
// (exp field in-range ~16%). Writes flag[0] = 1 if bf16.
// ---------------------------------------------------------------------------
__global__ void detect_kernel(const unsigned* __restrict__ x, int* __restrict__ flag) {
    __shared__ int cnt;
    if (threadIdx.x == 0) cnt = 0;
    __syncthreads();
    int c = 0;
    for (int i = threadIdx.x; i < 4096; i += 256) {
        const unsigned w = x[i];
        const unsigned e = (w >> 7) & 0xFF;   // low half-word's bf16 exponent field
        if (e >= 105 && e <= 140) ++c;
    }
    atomicAdd(&cnt, c);
    __syncthreads();
    if (threadIdx.x == 0) flag[0] = (cnt > 2300) ? 1 : 0;
}

// ---------------------------------------------------------------------------
// Generic tiled GEMM: C[M,N] = A[M,K] @ B[K,N], row-major, fp32 accumulate.
// BM=BN=64, BK=16, 256 threads, 4x4 micro-tile per thread.
// AMODE/BMODE: 0 = f32 fixed, 1 = bf16 fixed, 2 = runtime flag.
// EPI==1: store 2*sigmoid(acc).
// ---------------------------------------------------------------------------
template <int AMODE, int BMODE, typename TC, int EPI>
__global__ __launch_bounds__(256) void gemm_kernel(
    const void* __restrict__ A, int lda,
    const void* __restrict__ Bm, int ldb,
    TC* __restrict__ Cm, int ldc,
    int M, int N, int K, const int* __restrict__ flagp)
{
    int fl = 0;
    if (AMODE == 2 || BMODE == 2) fl = flagp[0];
    const int abf = (AMODE == 1) ? 1 : ((AMODE == 2) ? fl : 0);
    const int bbf = (BMODE == 1) ? 1 : ((BMODE == 2) ? fl : 0);

    __shared__ float As[16][68];   // transposed: As[k][m]
    __shared__ float Bs[16][68];   // Bs[k][n]
    const int tid = threadIdx.x;
    const int m0 = blockIdx.y * 64;
    const int n0 = blockIdx.x * 64;
    const int ty = tid >> 4, tx = tid & 15;
    float acc[4][4] = {{0.f}};

    const int ea = tid * 4;
    const int am = ea >> 4, ak = ea & 15;   // A tile 64x16
    const int bk = ea >> 6, bn = ea & 63;   // B tile 16x64

    for (int k0 = 0; k0 < K; k0 += 16) {
        const size_t aidx = (size_t)(m0 + am) * lda + (k0 + ak);
        #pragma unroll
        for (int i = 0; i < 4; ++i) As[ak + i][am] = dynload(A, aidx + i, abf);
        if (n0 + bn < N) {
            const size_t bidx = (size_t)(k0 + bk) * ldb + (n0 + bn);
            #pragma unroll
            for (int i = 0; i < 4; ++i) Bs[bk][bn + i] = dynload(Bm, bidx + i, bbf);
        } else {
            #pragma unroll
            for (int i = 0; i < 4; ++i) Bs[bk][bn + i] = 0.f;
        }
        __syncthreads();
        #pragma unroll
        for (int k = 0; k < 16; ++k) {
            float4 a4 = *(const float4*)&As[k][ty * 4];
            float4 b4 = *(const float4*)&Bs[k][tx * 4];
            float av[4] = {a4.x, a4.y, a4.z, a4.w};
            float bv[4] = {b4.x, b4.y, b4.z, b4.w};
            #pragma unroll
            for (int i = 0; i < 4; ++i)
                #pragma unroll
                for (int j = 0; j < 4; ++j)
                    acc[i][j] += av[i] * bv[j];
        }
        __syncthreads();
    }
    #pragma unroll
    for (int i = 0; i < 4; ++i) {
        const int row = m0 + ty * 4 + i;
        #pragma unroll
        for (int j = 0; j < 4; ++j) {
            const int col = n0 + tx * 4 + j;
            if (col < N) {
                float v = acc[i][j];
                if (EPI == 1) v = 2.f / (1.f + expf(-v));
                Cm[(size_t)row * ldc + col] = fromf<TC>(v);
            }
        }
    }
}

// ---------------------------------------------------------------------------
// Assemble q/k/v per (b,t): rope + rmsnorm for q,k; gated v with ve einsum.
// Block = 256 threads: 16 heads x 16 lanes, 8 dims per lane.
// ---------------------------------------------------------------------------
__global__ __launch_bounds__(256) void assemble_kernel(
    const float* __restrict__ down,    // [NT,1088]; cols 1024..1087 = k_rope_raw
    const bf16* __restrict__ qraw,     // [NT,2048]
    const bf16* __restrict__ kv,       // [NT,3072] (H x (64 nope + 128 v))
    const float* __restrict__ gates,   // [NT,80]
    const void* __restrict__ ve,       // [NT,8192] dyn
    const void* __restrict__ cosg,     // [NT,32]   dyn
    const void* __restrict__ sing,     // [NT,32]   dyn
    bf16* __restrict__ qo,             // [NT,2048]
    bf16* __restrict__ ko,
    bf16* __restrict__ vo,
    const int* __restrict__ flagp)
{
    const int fl = flagp[0];
    const int bt = blockIdx.x;
    const int tid = threadIdx.x;
    __shared__ float cs[32], sn[32], kr[64];
    if (tid < 32) {
        cs[tid] = dynload(cosg, (size_t)bt * 32 + tid, fl);
        sn[tid] = dynload(sing, (size_t)bt * 32 + tid, fl);
    }
    __syncthreads();
    if (tid < 64) {
        const float* rp = down + (size_t)bt * DOWN_N + 1024;
        const int d = tid;
        if (d < 32) kr[d] = rp[d] * cs[d] + rp[d + 32] * sn[d];
        else { const int r = d - 32; kr[d] = -rp[d - 32] * sn[r] + rp[d] * cs[r]; }
    }
    __syncthreads();

    const int h = tid >> 4;
    const int lane = tid & 15;
    const int d0 = lane * 8;

    // ---- Q: rope on dims [64,128), then rmsnorm over 128 ----
    const bf16* qr = qraw + (size_t)bt * Q_N + h * HD_;
    float vq[8];
    float ss = 0.f;
    #pragma unroll
    for (int i = 0; i < 8; ++i) {
        const int d = d0 + i;
        float xv = tof(qr[d]);
        if (d >= 64) {
            if (d < 96) { const int r = d - 64; xv = xv * cs[r] + tof(qr[d + 32]) * sn[r]; }
            else        { const int r = d - 96; xv = -tof(qr[d - 32]) * sn[r] + xv * cs[r]; }
        }
        vq[i] = xv;
        ss += xv * xv;
    }
    #pragma unroll
    for (int off = 1; off < 16; off <<= 1) ss += __shfl_xor(ss, off);
    float rms = rsqrtf(ss * (1.f / 128.f) + EPS_);
    bf16* qop = qo + (size_t)bt * Q_N + h * HD_ + d0;
    #pragma unroll
    for (int i = 0; i < 8; ++i) qop[i] = fromf<bf16>(vq[i] * rms);

    // ---- K: [k_nope(64) | roped k_rope(64) broadcast], rmsnorm over 128 ----
    const bf16* kvp = kv + (size_t)bt * KV_N + h * 192;
    float vk[8];
    ss = 0.f;
    #pragma unroll
    for (int i = 0; i < 8; ++i) {
        const int d = d0 + i;
        const float xv = (d < 64) ? tof(kvp[d]) : kr[d - 64];
        vk[i] = xv;
        ss += xv * xv;
    }
    #pragma unroll
    for (int off = 1; off < 16; off <<= 1) ss += __shfl_xor(ss, off);
    rms = rsqrtf(ss * (1.f / 128.f) + EPS_);
    bf16* kop = ko + (size_t)bt * Q_N + h * HD_ + d0;
    #pragma unroll
    for (int i = 0; i < 8; ++i) kop[i] = fromf<bf16>(vk[i] * rms);

    // ---- V: g0 * v + sum_m g[m+1] * ve[m] ----
    float g[5];
    #pragma unroll
    for (int j = 0; j < 5; ++j) g[j] = gates[(size_t)bt * G_N + h * 5 + j];
    const bf16* vp = kvp + 64;
    const size_t vebase = (size_t)bt * 8192 + h * HD_;
    bf16* vop = vo + (size_t)bt * Q_N + h * HD_ + d0;
    #pragma unroll
    for (int i = 0; i < 8; ++i) {
        const int d = d0 + i;
        float val = g[0] * tof(vp[d]);
        #pragma unroll
        for (int m = 0; m < 4; ++m) val += g[1 + m] * dynload(ve, vebase + m * 2048 + d, fl);
        vop[i] = fromf<bf16>(val);
    }
}

// ---------------------------------------------------------------------------
// Flash attention, causal + window. 32 queries per block, 32-key tiles.
// ---------------------------------------------------------------------------
__global__ __launch_bounds__(256) void attn_kernel(
    const bf16* __restrict__ q,
    const bf16* __restrict__ k,
    const bf16* __restrict__ v,
    float* __restrict__ y,
    const int* __restrict__ wptr)
{
    const int m0 = blockIdx.x * 32;
    const int h  = blockIdx.y;
    const int b  = blockIdx.z;
    const int W  = wptr[0];
    const int tid = threadIdx.x;

    __shared__ float qs[32][132];
    __shared__ float ks[32][132];
    __shared__ float vs[32][132];
    __shared__ float sc[32][33];
    __shared__ float m_s[32], l_s[32], a_s[32];

    const float scale = 0.08838834764831845f;  // 1/sqrt(128)

    const size_t qbase = ((size_t)(b * T_ + m0)) * Q_N + (size_t)h * HD_;
    for (int e = tid; e < 32 * 128; e += 256) {
        const int r = e >> 7, d = e & 127;
        qs[r][d] = tof(q[qbase + (size_t)r * Q_N + d]) * scale;
    }
    if (tid < 32) { m_s[tid] = -1e30f; l_s[tid] = 0.f; }

    float o[16];
    #pragma unroll
    for (int i = 0; i < 16; ++i) o[i] = 0.f;

    const int r  = tid >> 3;
    const int cb = (tid & 7) * 4;
    const int oc = (tid & 7) * 16;

    __syncthreads();

    for (int n0 = 0; n0 <= m0; n0 += 32) {
        const size_t kbase = ((size_t)(b * T_ + n0)) * Q_N + (size_t)h * HD_;
        for (int e = tid; e < 32 * 128; e += 256) {
            const int rr = e >> 7, d = e & 127;
            ks[rr][d] = tof(k[kbase + (size_t)rr * Q_N + d]);
            vs[rr][d] = tof(v[kbase + (size_t)rr * Q_N + d]);
        }
        __syncthreads();

        float a0 = 0.f, a1 = 0.f, a2 = 0.f, a3 = 0.f;
        for (int d = 0; d < 128; d += 4) {
            const float4 q4 = *(const float4*)&qs[r][d];
            const float4 k0 = *(const float4*)&ks[cb + 0][d];
            const float4 k1 = *(const float4*)&ks[cb + 1][d];
            const float4 k2 = *(const float4*)&ks[cb + 2][d];
            const float4 k3 = *(const float4*)&ks[cb + 3][d];
            a0 += q4.x * k0.x + q4.y * k0.y + q4.z * k0.z + q4.w * k0.w;
            a1 += q4.x * k1.x + q4.y * k1.y + q4.z * k1.z + q4.w * k1.w;
            a2 += q4.x * k2.x + q4.y * k2.y + q4.z * k2.z + q4.w * k2.w;
            a3 += q4.x * k3.x + q4.y * k3.y + q4.z * k3.z + q4.w * k3.w;
        }
        float s4[4] = {a0, a1, a2, a3};
        const int ti = m0 + r;
        #pragma unroll
        for (int cc = 0; cc < 4; ++cc) {
            const int si = n0 + cb + cc;
            const bool ok = (si <= ti) && (ti - si <= W);
            if (!ok) s4[cc] = -1e30f;
        }
        float rowmax = fmaxf(fmaxf(s4[0], s4[1]), fmaxf(s4[2], s4[3]));
        #pragma unroll
        for (int off = 1; off < 8; off <<= 1) rowmax = fmaxf(rowmax, __shfl_xor(rowmax, off));
        const float m_old = m_s[r];
        const float m_new = fmaxf(m_old, rowmax);
        float psum = 0.f;
        #pragma unroll
        for (int cc = 0; cc < 4; ++cc) {
            const float p = (s4[cc] < -0.5e30f) ? 0.f : expf(s4[cc] - m_new);
            sc[r][cb + cc] = p;
            psum += p;
        }
        #pragma unroll
        for (int off = 1; off < 8; off <<= 1) psum += __shfl_xor(psum, off);
        if ((tid & 7) == 0) {
            const float alpha = expf(m_old - m_new);
            a_s[r] = alpha;
            m_s[r] = m_new;
            l_s[r] = l_s[r] * alpha + psum;
        }
        __syncthreads();

        const float alpha = a_s[r];
        #pragma unroll
        for (int i = 0; i < 16; ++i) o[i] *= alpha;
        for (int c = 0; c < 32; ++c) {
            const float p = sc[r][c];
            const float4* vp4 = (const float4*)&vs[c][oc];
            const float4 v0 = vp4[0], v1 = vp4[1], v2 = vp4[2], v3 = vp4[3];
            o[0]  += p * v0.x; o[1]  += p * v0.y; o[2]  += p * v0.z; o[3]  += p * v0.w;
            o[4]  += p * v1.x; o[5]  += p * v1.y; o[6]  += p * v1.z; o[7]  += p * v1.w;
            o[8]  += p * v2.x; o[9]  += p * v2.y; o[10] += p * v2.z; o[11] += p * v2.w;
            o[12] += p * v3.x; o[13] += p * v3.y; o[14] += p * v3.z; o[15] += p * v3.w;
        }
        __syncthreads();
    }

    const float inv = 1.f / l_s[r];
    float* yp = y + ((size_t)(b * T_ + m0 + r)) * Q_N + (size_t)h * HD_ + oc;
    #pragma unroll
    for (int i4 = 0; i4 < 4; ++i4) {
        float4 t;
        t.x = o[i4 * 4 + 0] * inv;
        t.y = o[i4 * 4 + 1] * inv;
        t.z = o[i4 * 4 + 2] * inv;
        t.w = o[i4 * 4 + 3] * inv;
        *(float4*)&yp[i4 * 4] = t;
    }
}

// ---------------------------------------------------------------------------
extern "C" void kernel_launch(void* const* d_in, const int* in_sizes, int n_in,
                              void* d_out, int out_size, void* d_ws, size_t ws_size,
                              hipStream_t stream)
{
    const void* x      = d_in[0];
    const void* ve     = d_in[1];
    const void* cosg   = d_in[2];
    const void* sing   = d_in[3];
    const void* w_down = d_in[4];
    const void* w_ukv  = d_in[5];
    const void* w_uq   = d_in[6];
    const void* w_gate = d_in[7];
    const void* w_proj = d_in[8];
    const int*  wsz    = (const int*)d_in[9];
    float* out = (float*)d_out;   // reference output dtype is float32

    // workspace layout (~145 MB total)
    char* p = (char*)d_ws;
    float* down  = (float*)p;  p += (size_t)NT_ * DOWN_N * 4;
    bf16*  kvb   = (bf16*)p;   p += (size_t)NT_ * KV_N * 2;
    bf16*  qraw  = (bf16*)p;   p += (size_t)NT_ * Q_N * 2;
    float* gates = (float*)p;  p += (size_t)NT_ * G_N * 4;
    bf16*  qn    = (bf16*)p;   p += (size_t)NT_ * Q_N * 2;
    bf16*  kn    = (bf16*)p;   p += (size_t)NT_ * Q_N * 2;
    bf16*  vn    = (bf16*)p;   p += (size_t)NT_ * Q_N * 2;
    float* yb    = (float*)p;  p += (size_t)NT_ * Q_N * 4;
    int*   flag  = (int*)p;    p += 256;

    dim3 blk(256);
    // 0) input dtype detection (writes flag[0]: 0=f32, 1=bf16)
    hipLaunchKernelGGL(detect_kernel, dim3(1), blk, 0, stream, (const unsigned*)x, flag);
    // down = x @ w_down  [4096,2048]x[2048,1088] -> f32
    hipLaunchKernelGGL((gemm_kernel<2, 2, float, 0>), dim3(DOWN_N / 64, NT_ / 64), blk, 0, stream,
                       x, C_, w_down, DOWN_N, down, DOWN_N, NT_, DOWN_N, C_, flag);
    // gates = 2*sigmoid(x @ w_gate)  [4096,2048]x[2048,80] -> f32
    hipLaunchKernelGGL((gemm_kernel<2, 2, float, 1>), dim3(2, NT_ / 64), blk, 0, stream,
                       x, C_, w_gate, G_N, gates, G_N, NT_, G_N, C_, flag);
    // kv = c_kv @ w_ukv  [4096,512]x[512,3072] -> bf16
    hipLaunchKernelGGL((gemm_kernel<0, 2, bf16, 0>), dim3(KV_N / 64, NT_ / 64), blk, 0, stream,
                       down, DOWN_N, w_ukv, KV_N, kvb, KV_N, NT_, KV_N, 512, flag);
    // q_raw = c_q @ w_uq  [4096,512]x[512,2048] -> bf16
    hipLaunchKernelGGL((gemm_kernel<0, 2, bf16, 0>), dim3(Q_N / 64, NT_ / 64), blk, 0, stream,
                       (const void*)(down + 512), DOWN_N, w_uq, Q_N, qraw, Q_N, NT_, Q_N, 512, flag);
    // assemble q/k/v
    hipLaunchKernelGGL(assemble_kernel, dim3(NT_), blk, 0, stream,
                       down, qraw, kvb, gates, ve, cosg, sing, qn, kn, vn, flag);
    // flash attention -> y (f32)
    hipLaunchKernelGGL(attn_kernel, dim3(T_ / 32, H_, B_), blk, 0, stream,
                       qn, kn, vn, yb, wsz);
    // out = y @ w_proj  [4096,2048]x[2048,2048] -> f32
    hipLaunchKernelGGL((gemm_kernel<0, 2, float, 0>), dim3(Q_N / 64, NT_ / 64), blk, 0, stream,
                       yb, Q_N, w_proj, C_, out, C_, NT_, C_, Q_N, flag);
}

// Round 4
// 978.467 us; speedup vs baseline: 3.9560x; 3.9560x over previous
//
#include <hip/hip_runtime.h>

typedef unsigned short u16;
typedef __bf16 bfv8 __attribute__((ext_vector_type(8)));
typedef float f32x4 __attribute__((ext_vector_type(4)));
typedef u16 u16x8 __attribute__((ext_vector_type(8)));

#define B_      2
#define T_      2048
#define C_      2048
#define H_      16
#define HD_     128
#define NT_     (B_ * T_)
#define DOWN_N  1088
#define KV_N    3072
#define Q_N     2048
#define G_N     80
#define EPS_    1.1920929e-07f
// softmax scale (1/sqrt(128)) * log2(e), for exp2-domain online softmax
#define CEXP    0.12751879524580262f

__device__ __forceinline__ float b2f(u16 u) {
    union { unsigned u; float f; } c; c.u = ((unsigned)u) << 16; return c.f;
}
__device__ __forceinline__ u16 f2b(float f) {
    union { float f; unsigned u; } c; c.f = f;
    return (u16)((c.u + 0x7FFFu + ((c.u >> 16) & 1u)) >> 16);
}
// Runtime-dtype load: bf==0 -> f32, bf==1 -> bf16
__device__ __forceinline__ float dynload(const void* p, size_t i, int bf) {
    if (bf) return b2f(((const u16*)p)[i]);
    return ((const float*)p)[i];
}

// ---------------------------------------------------------------------------
// Input dtype detector (writes flag[0] = 1 if bf16). Kept from round 3.
// ---------------------------------------------------------------------------
__global__ void detect_kernel(const unsigned* __restrict__ x, int* __restrict__ flag) {
    __shared__ int cnt;
    if (threadIdx.x == 0) cnt = 0;
    __syncthreads();
    int c = 0;
    for (int i = threadIdx.x; i < 4096; i += 256) {
        const unsigned w = x[i];
        const unsigned e = (w >> 7) & 0xFF;
        if (e >= 105 && e <= 140) ++c;
    }
    atomicAdd(&cnt, c);
    __syncthreads();
    if (threadIdx.x == 0) flag[0] = (cnt > 2300) ? 1 : 0;
}

// ---------------------------------------------------------------------------
// Elementwise cast (dyn f32/bf16 -> bf16), 8 elems/thread.
// ---------------------------------------------------------------------------
__global__ __launch_bounds__(256) void cast_kernel(
    const void* __restrict__ in, u16* __restrict__ out, int n, const int* __restrict__ flagp)
{
    const int fl = flagp[0];
    const int i0 = (blockIdx.x * 256 + threadIdx.x) * 8;
    if (i0 + 8 > n) return;
    u16x8 o;
    #pragma unroll
    for (int i = 0; i < 8; ++i) o[i] = f2b(dynload(in, (size_t)i0 + i, fl));
    *(u16x8*)(out + i0) = o;
}

// ---------------------------------------------------------------------------
// Transpose + cast: W[K][N] (dyn) -> W_T[N][K] (bf16). 32x32 LDS tiles.
// ---------------------------------------------------------------------------
__global__ __launch_bounds__(256) void tcast_kernel(
    const void* __restrict__ in, u16* __restrict__ out, int K, int N, const int* __restrict__ flagp)
{
    const int fl = flagp[0];
    __shared__ float sf[32][33];
    const int n0 = blockIdx.x * 32, k0 = blockIdx.y * 32;
    const int tx = threadIdx.x & 31, ty = threadIdx.x >> 5;
    #pragma unroll
    for (int i = 0; i < 4; ++i)
        sf[ty + 8 * i][tx] = dynload(in, (size_t)(k0 + ty + 8 * i) * N + n0 + tx, fl);
    __syncthreads();
    #pragma unroll
    for (int i = 0; i < 4; ++i)
        out[(size_t)(n0 + ty + 8 * i) * K + k0 + tx] = f2b(sf[tx][ty + 8 * i]);
}

// ---------------------------------------------------------------------------
// MFMA GEMM: C[M,N] = A[M,K] @ B[K,N], A row-major bf16, BT = B^T row-major
// bf16 [N][K]. 128x128 tile, BK=32, 4 waves each 64x64 (4x4 of 16x16x32).
// ---------------------------------------------------------------------------
__device__ __forceinline__ void stc(u16* p, float v)  { *p = f2b(v); }
__device__ __forceinline__ void stc(float* p, float v){ *p = v; }

template <typename TC>
__global__ __launch_bounds__(256) void mfma_gemm(
    const u16* __restrict__ A, int lda,
    const u16* __restrict__ BT, int ldb,
    TC* __restrict__ Cm, int ldc,
    int M, int N, int K)
{
    __shared__ u16 As[128][40];   // [m][k], stride 40 (pad 8) keeps 16B align
    __shared__ u16 Bs[128][40];   // [n][k]
    const int tid = threadIdx.x;
    const int m0 = blockIdx.y * 128, n0 = blockIdx.x * 128;
    const int w = tid >> 6, l = tid & 63;
    const int wm = (w >> 1) * 64, wn = (w & 1) * 64;
    const int lr = l & 15, lq = l >> 4;
    const int sr = tid >> 1, sh = (tid & 1) * 16;   // staging: row, 16-elem half

    f32x4 acc[4][4];
    #pragma unroll
    for (int i = 0; i < 4; ++i)
        #pragma unroll
        for (int j = 0; j < 4; ++j) acc[i][j] = (f32x4){0.f, 0.f, 0.f, 0.f};

    const bool bvalid = (n0 + sr) < N;
    const u16* arow = A + (size_t)(m0 + sr) * lda + sh;
    const u16* brow = BT + (size_t)(bvalid ? (n0 + sr) : 0) * ldb + sh;

    for (int k0 = 0; k0 < K; k0 += 32) {
        u16x8 a0 = *(const u16x8*)(arow + k0);
        u16x8 a1 = *(const u16x8*)(arow + k0 + 8);
        u16x8 b0 = {0,0,0,0,0,0,0,0}, b1 = {0,0,0,0,0,0,0,0};
        if (bvalid) { b0 = *(const u16x8*)(brow + k0); b1 = *(const u16x8*)(brow + k0 + 8); }
        *(u16x8*)&As[sr][sh]     = a0;
        *(u16x8*)&As[sr][sh + 8] = a1;
        *(u16x8*)&Bs[sr][sh]     = b0;
        *(u16x8*)&Bs[sr][sh + 8] = b1;
        __syncthreads();
        bfv8 af[4], bf[4];
        #pragma unroll
        for (int mi = 0; mi < 4; ++mi) af[mi] = *(const bfv8*)&As[wm + mi * 16 + lr][lq * 8];
        #pragma unroll
        for (int ni = 0; ni < 4; ++ni) bf[ni] = *(const bfv8*)&Bs[wn + ni * 16 + lr][lq * 8];
        #pragma unroll
        for (int mi = 0; mi < 4; ++mi)
            #pragma unroll
            for (int ni = 0; ni < 4; ++ni)
                acc[mi][ni] = __builtin_amdgcn_mfma_f32_16x16x32_bf16(af[mi], bf[ni], acc[mi][ni], 0, 0, 0);
        __syncthreads();
    }

    #pragma unroll
    for (int mi = 0; mi < 4; ++mi) {
        #pragma unroll
        for (int ni = 0; ni < 4; ++ni) {
            const int col = n0 + wn + ni * 16 + lr;
            if (col < N) {
                #pragma unroll
                for (int r = 0; r < 4; ++r) {
                    const int row = m0 + wm + mi * 16 + lq * 4 + r;
                    stc(&Cm[(size_t)row * ldc + col], acc[mi][ni][r]);
                }
            }
        }
    }
}

// ---------------------------------------------------------------------------
// Gates GEMM (VALU, f32): gates = 2*sigmoid(x @ w_gate). N=80 small.
// ---------------------------------------------------------------------------
__global__ __launch_bounds__(256) void gates_gemm(
    const void* __restrict__ A, int lda,
    const void* __restrict__ Bm, int ldb,
    float* __restrict__ Cm, int ldc,
    int M, int N, int K, const int* __restrict__ flagp)
{
    const int fl = flagp[0];
    __shared__ float As[16][68];
    __shared__ float Bs[16][68];
    const int tid = threadIdx.x;
    const int m0 = blockIdx.y * 64;
    const int n0 = blockIdx.x * 64;
    const int ty = tid >> 4, tx = tid & 15;
    float acc[4][4] = {{0.f}};
    const int ea = tid * 4;
    const int am = ea >> 4, ak = ea & 15;
    const int bk = ea >> 6, bn = ea & 63;

    for (int k0 = 0; k0 < K; k0 += 16) {
        const size_t aidx = (size_t)(m0 + am) * lda + (k0 + ak);
        #pragma unroll
        for (int i = 0; i < 4; ++i) As[ak + i][am] = dynload(A, aidx + i, fl);
        if (n0 + bn < N) {
            const size_t bidx = (size_t)(k0 + bk) * ldb + (n0 + bn);
            #pragma unroll
            for (int i = 0; i < 4; ++i) Bs[bk][bn + i] = dynload(Bm, bidx + i, fl);
        } else {
            #pragma unroll
            for (int i = 0; i < 4; ++i) Bs[bk][bn + i] = 0.f;
        }
        __syncthreads();
        #pragma unroll
        for (int k = 0; k < 16; ++k) {
            float4 a4 = *(const float4*)&As[k][ty * 4];
            float4 b4 = *(const float4*)&Bs[k][tx * 4];
            float av[4] = {a4.x, a4.y, a4.z, a4.w};
            float bv[4] = {b4.x, b4.y, b4.z, b4.w};
            #pragma unroll
            for (int i = 0; i < 4; ++i)
                #pragma unroll
                for (int j = 0; j < 4; ++j) acc[i][j] += av[i] * bv[j];
        }
        __syncthreads();
    }
    #pragma unroll
    for (int i = 0; i < 4; ++i) {
        const int row = m0 + ty * 4 + i;
        #pragma unroll
        for (int j = 0; j < 4; ++j) {
            const int col = n0 + tx * 4 + j;
            if (col < N) Cm[(size_t)row * ldc + col] = 2.f / (1.f + expf(-acc[i][j]));
        }
    }
}

// ---------------------------------------------------------------------------
// Assemble q/k/v per (b,t): rope + rmsnorm for q,k; gated v with ve einsum.
// ---------------------------------------------------------------------------
__global__ __launch_bounds__(256) void assemble_kernel(
    const u16* __restrict__ down,      // [NT,1088] bf16; cols 1024.. = k_rope_raw
    const u16* __restrict__ qraw,      // [NT,2048] bf16
    const u16* __restrict__ kv,        // [NT,3072] bf16
    const float* __restrict__ gates,   // [NT,80]
    const void* __restrict__ ve,       // [NT,8192] dyn
    const void* __restrict__ cosg,     // [NT,32]   dyn
    const void* __restrict__ sing,     // [NT,32]   dyn
    u16* __restrict__ qo, u16* __restrict__ ko, u16* __restrict__ vo,
    const int* __restrict__ flagp)
{
    const int fl = flagp[0];
    const int bt = blockIdx.x;
    const int tid = threadIdx.x;
    __shared__ float cs[32], sn[32], kr[64];
    if (tid < 32) {
        cs[tid] = dynload(cosg, (size_t)bt * 32 + tid, fl);
        sn[tid] = dynload(sing, (size_t)bt * 32 + tid, fl);
    }
    __syncthreads();
    if (tid < 64) {
        const u16* rp = down + (size_t)bt * DOWN_N + 1024;
        const int d = tid;
        if (d < 32) kr[d] = b2f(rp[d]) * cs[d] + b2f(rp[d + 32]) * sn[d];
        else { const int r = d - 32; kr[d] = -b2f(rp[d - 32]) * sn[r] + b2f(rp[d]) * cs[r]; }
    }
    __syncthreads();

    const int h = tid >> 4;
    const int lane = tid & 15;
    const int d0 = lane * 8;

    // Q: rope on [64,128), rmsnorm over 128
    const u16* qr = qraw + (size_t)bt * Q_N + h * HD_;
    float vq[8];
    float ss = 0.f;
    #pragma unroll
    for (int i = 0; i < 8; ++i) {
        const int d = d0 + i;
        float xv = b2f(qr[d]);
        if (d >= 64) {
            if (d < 96) { const int r = d - 64; xv = xv * cs[r] + b2f(qr[d + 32]) * sn[r]; }
            else        { const int r = d - 96; xv = -b2f(qr[d - 32]) * sn[r] + xv * cs[r]; }
        }
        vq[i] = xv; ss += xv * xv;
    }
    #pragma unroll
    for (int off = 1; off < 16; off <<= 1) ss += __shfl_xor(ss, off);
    float rms = rsqrtf(ss * (1.f / 128.f) + EPS_);
    u16* qop = qo + (size_t)bt * Q_N + h * HD_ + d0;
    #pragma unroll
    for (int i = 0; i < 8; ++i) qop[i] = f2b(vq[i] * rms);

    // K: [k_nope(64) | roped k_rope(64)], rmsnorm over 128
    const u16* kvp = kv + (size_t)bt * KV_N + h * 192;
    float vk[8];
    ss = 0.f;
    #pragma unroll
    for (int i = 0; i < 8; ++i) {
        const int d = d0 + i;
        const float xv = (d < 64) ? b2f(kvp[d]) : kr[d - 64];
        vk[i] = xv; ss += xv * xv;
    }
    #pragma unroll
    for (int off = 1; off < 16; off <<= 1) ss += __shfl_xor(ss, off);
    rms = rsqrtf(ss * (1.f / 128.f) + EPS_);
    u16* kop = ko + (size_t)bt * Q_N + h * HD_ + d0;
    #pragma unroll
    for (int i = 0; i < 8; ++i) kop[i] = f2b(vk[i] * rms);

    // V: g0 * v + sum_m g[m+1] * ve[m]
    float g[5];
    #pragma unroll
    for (int j = 0; j < 5; ++j) g[j] = gates[(size_t)bt * G_N + h * 5 + j];
    const u16* vp = kvp + 64;
    const size_t vebase = (size_t)bt * 8192 + h * HD_;
    u16* vop = vo + (size_t)bt * Q_N + h * HD_ + d0;
    #pragma unroll
    for (int i = 0; i < 8; ++i) {
        const int d = d0 + i;
        float val = g[0] * b2f(vp[d]);
        #pragma unroll
        for (int m = 0; m < 4; ++m) val += g[1 + m] * dynload(ve, vebase + m * 2048 + d, fl);
        vop[i] = f2b(val);
    }
}

// ---------------------------------------------------------------------------
// V transpose: vn [b][t][h][d] -> vt [(b,h)][d][t]   (bf16, 64x64 tiles)
// ---------------------------------------------------------------------------
__global__ __launch_bounds__(256) void vtrans_kernel(
    const u16* __restrict__ vn, u16* __restrict__ vt)
{
    __shared__ u16 s[64][72];
    const int t0 = blockIdx.x * 64;
    const int d0 = blockIdx.y * 64;
    const int bh = blockIdx.z;          // b*H + h
    const int tid = threadIdx.x;
    {
        const int tt = tid >> 2, seg = tid & 3;
        const u16* p = vn + ((size_t)((bh >> 4) * T_) + t0 + tt) * 2048 + (bh & 15) * 128 + d0 + seg * 16;
        u16x8 v0 = *(const u16x8*)(p);
        u16x8 v1 = *(const u16x8*)(p + 8);
        *(u16x8*)&s[tt][seg * 16]     = v0;
        *(u16x8*)&s[tt][seg * 16 + 8] = v1;
    }
    __syncthreads();
    {
        const int dd = tid >> 2, tseg = tid & 3;
        u16* q = vt + ((size_t)(bh * 128) + d0 + dd) * T_ + t0 + tseg * 16;
        #pragma unroll
        for (int g = 0; g < 2; ++g) {
            u16x8 o;
            #pragma unroll
            for (int i = 0; i < 8; ++i) o[i] = s[tseg * 16 + g * 8 + i][dd];
            *(u16x8*)(q + g * 8) = o;
        }
    }
}

// ---------------------------------------------------------------------------
// MFMA flash attention. Block: 64 Q rows x (b,h); 4 waves each own 16 Q rows.
// K tiles of 64 keys. Online softmax in registers (exp2 domain).
// ---------------------------------------------------------------------------
__global__ __launch_bounds__(256) void attn_mfma(
    const u16* __restrict__ qn, const u16* __restrict__ kn,
    const u16* __restrict__ vt, u16* __restrict__ yb,
    const int* __restrict__ wptr)
{
    __shared__ u16 Ks[64][136];      // K tile row-major [key][d]
    __shared__ u16 VTs[128][72];     // V tile transposed [d][key]
    __shared__ u16 Ps[4][16][72];    // per-wave P round-trip [qrow][key]

    const int m0 = blockIdx.x * 64;
    const int h = blockIdx.y, b = blockIdx.z;
    const int W = wptr[0];
    const int tid = threadIdx.x;
    const int w = tid >> 6, l = tid & 63;
    const int lr = l & 15, lq = l >> 4;
    const int qr0 = m0 + w * 16;

    // Q fragments, held in registers for whole block
    bfv8 qf[4];
    {
        const u16* qp = qn + ((size_t)(b * T_) + qr0 + lr) * 2048 + h * 128 + lq * 8;
        #pragma unroll
        for (int kk = 0; kk < 4; ++kk) qf[kk] = *(const bfv8*)(qp + kk * 32);
    }

    f32x4 oacc[8];
    #pragma unroll
    for (int i = 0; i < 8; ++i) oacc[i] = (f32x4){0.f, 0.f, 0.f, 0.f};
    float m_r[4] = {-1e30f, -1e30f, -1e30f, -1e30f};
    float l_r[4] = {0.f, 0.f, 0.f, 0.f};

    const int kkey = tid >> 2, kseg = tid & 3;   // K staging: 64 keys x 4 segs
    const int vd = tid >> 1, vh = tid & 1;       // V staging: 128 d x 2 halves

    int n_start = m0 - W - 63; if (n_start < 0) n_start = 0; n_start &= ~63;

    for (int n0 = n_start; n0 <= m0; n0 += 64) {
        {   // stage K row-major
            const u16* kp = kn + ((size_t)(b * T_) + n0 + kkey) * 2048 + h * 128 + kseg * 32;
            u16x8 t0 = *(const u16x8*)(kp);
            u16x8 t1 = *(const u16x8*)(kp + 8);
            u16x8 t2 = *(const u16x8*)(kp + 16);
            u16x8 t3 = *(const u16x8*)(kp + 24);
            *(u16x8*)&Ks[kkey][kseg * 32]      = t0;
            *(u16x8*)&Ks[kkey][kseg * 32 + 8]  = t1;
            *(u16x8*)&Ks[kkey][kseg * 32 + 16] = t2;
            *(u16x8*)&Ks[kkey][kseg * 32 + 24] = t3;
            // stage V^T (already d-major in global)
            const u16* vp = vt + ((size_t)(b * H_ + h) * 128 + vd) * T_ + n0 + vh * 32;
            u16x8 v0 = *(const u16x8*)(vp);
            u16x8 v1 = *(const u16x8*)(vp + 8);
            u16x8 v2 = *(const u16x8*)(vp + 16);
            u16x8 v3 = *(const u16x8*)(vp + 24);
            *(u16x8*)&VTs[vd][vh * 32]      = v0;
            *(u16x8*)&VTs[vd][vh * 32 + 8]  = v1;
            *(u16x8*)&VTs[vd][vh * 32 + 16] = v2;
            *(u16x8*)&VTs[vd][vh * 32 + 24] = v3;
        }
        __syncthreads();

        // S = Q K^T  (4 key-frags of 16)
        f32x4 s[4];
        #pragma unroll
        for (int f = 0; f < 4; ++f) {
            s[f] = (f32x4){0.f, 0.f, 0.f, 0.f};
            #pragma unroll
            for (int kk = 0; kk < 4; ++kk) {
                bfv8 kf = *(const bfv8*)&Ks[f * 16 + lr][kk * 32 + lq * 8];
                s[f] = __builtin_amdgcn_mfma_f32_16x16x32_bf16(qf[kk], kf, s[f], 0, 0, 0);
            }
        }

        // mask (wave-uniform branch)
        if ((n0 + 63 > qr0) || (qr0 + 15 - n0 > W)) {
            #pragma unroll
            for (int f = 0; f < 4; ++f) {
                const int si = n0 + f * 16 + lr;
                #pragma unroll
                for (int r = 0; r < 4; ++r) {
                    const int ti = qr0 + lq * 4 + r;
                    if (si > ti || ti - si > W) s[f][r] = -1e30f;
                }
            }
        }

        // online softmax (rows live in 16-lane groups; xor 1,2,4,8 stays in-group)
        float al_r[4];
        #pragma unroll
        for (int r = 0; r < 4; ++r) {
            float mx = fmaxf(fmaxf(s[0][r], s[1][r]), fmaxf(s[2][r], s[3][r]));
            mx = fmaxf(mx, __shfl_xor(mx, 1));
            mx = fmaxf(mx, __shfl_xor(mx, 2));
            mx = fmaxf(mx, __shfl_xor(mx, 4));
            mx = fmaxf(mx, __shfl_xor(mx, 8));
            const float mnew = fmaxf(m_r[r], mx);
            al_r[r] = exp2f((m_r[r] - mnew) * CEXP);
            float ps = 0.f;
            #pragma unroll
            for (int f = 0; f < 4; ++f) {
                const float sv = s[f][r];
                const float pv = (sv <= -0.9e30f) ? 0.f : exp2f((sv - mnew) * CEXP);
                s[f][r] = pv; ps += pv;
            }
            ps += __shfl_xor(ps, 1);
            ps += __shfl_xor(ps, 2);
            ps += __shfl_xor(ps, 4);
            ps += __shfl_xor(ps, 8);
            l_r[r] = l_r[r] * al_r[r] + ps;
            m_r[r] = mnew;
        }
        #pragma unroll
        for (int od = 0; od < 8; ++od)
            #pragma unroll
            for (int r = 0; r < 4; ++r) oacc[od][r] *= al_r[r];

        // P -> LDS (C-layout scatter), then read back in A-layout
        #pragma unroll
        for (int f = 0; f < 4; ++f)
            #pragma unroll
            for (int r = 0; r < 4; ++r)
                Ps[w][lq * 4 + r][f * 16 + lr] = f2b(s[f][r]);
        __syncthreads();

        // O += P V
        #pragma unroll
        for (int kk2 = 0; kk2 < 2; ++kk2) {
            bfv8 pf = *(const bfv8*)&Ps[w][lr][kk2 * 32 + lq * 8];
            #pragma unroll
            for (int od = 0; od < 8; ++od) {
                bfv8 vf = *(const bfv8*)&VTs[od * 16 + lr][kk2 * 32 + lq * 8];
                oacc[od] = __builtin_amdgcn_mfma_f32_16x16x32_bf16(pf, vf, oacc[od], 0, 0, 0);
            }
        }
        __syncthreads();
    }

    float inv[4];
    #pragma unroll
    for (int r = 0; r < 4; ++r) inv[r] = 1.f / l_r[r];
    #pragma unroll
    for (int od = 0; od < 8; ++od)
        #pragma unroll
        for (int r = 0; r < 4; ++r) {
            const size_t idx = ((size_t)(b * T_) + qr0 + lq * 4 + r) * 2048 + h * 128 + od * 16 + lr;
            yb[idx] = f2b(oacc[od][r] * inv[r]);
        }
}

// ---------------------------------------------------------------------------
extern "C" void kernel_launch(void* const* d_in, const int* in_sizes, int n_in,
                              void* d_out, int out_size, void* d_ws, size_t ws_size,
                              hipStream_t stream)
{
    const void* x      = d_in[0];
    const void* ve     = d_in[1];
    const void* cosg   = d_in[2];
    const void* sing   = d_in[3];
    const void* w_down = d_in[4];
    const void* w_ukv  = d_in[5];
    const void* w_uq   = d_in[6];
    const void* w_gate = d_in[7];
    const void* w_proj = d_in[8];
    const int*  wsz    = (const int*)d_in[9];
    float* out = (float*)d_out;

    // workspace (~137.5 MB)
    char* p = (char*)d_ws;
    u16* xbf    = (u16*)p; p += (size_t)NT_ * C_ * 2;        // reused as qn
    u16* wdT    = (u16*)p; p += (size_t)DOWN_N * C_ * 2;
    u16* wukvT  = (u16*)p; p += (size_t)KV_N * 512 * 2;
    u16* wuqT   = (u16*)p; p += (size_t)Q_N * 512 * 2;
    u16* wpT    = (u16*)p; p += (size_t)C_ * C_ * 2;
    u16* downb  = (u16*)p; p += (size_t)NT_ * DOWN_N * 2;
    float* gates= (float*)p; p += (size_t)NT_ * G_N * 4;
    u16* kvb    = (u16*)p; p += (size_t)NT_ * KV_N * 2;
    u16* qraw   = (u16*)p; p += (size_t)NT_ * Q_N * 2;       // reused as y_bf
    u16* kn     = (u16*)p; p += (size_t)NT_ * Q_N * 2;
    u16* vn     = (u16*)p; p += (size_t)NT_ * Q_N * 2;
    u16* vtb    = (u16*)p; p += (size_t)NT_ * Q_N * 2;
    int* flag   = (int*)p; p += 256;
    u16* qn  = xbf;    // x_bf dead after down GEMM
    u16* ybf = qraw;   // qraw dead after assemble

    dim3 blk(256);
    detect_kernel<<<1, blk, 0, stream>>>((const unsigned*)x, flag);
    cast_kernel<<<dim3(NT_ * C_ / (256 * 8)), blk, 0, stream>>>(x, xbf, NT_ * C_, flag);
    tcast_kernel<<<dim3(DOWN_N / 32, C_ / 32), blk, 0, stream>>>(w_down, wdT, C_, DOWN_N, flag);
    tcast_kernel<<<dim3(KV_N / 32, 512 / 32), blk, 0, stream>>>(w_ukv, wukvT, 512, KV_N, flag);
    tcast_kernel<<<dim3(Q_N / 32, 512 / 32), blk, 0, stream>>>(w_uq, wuqT, 512, Q_N, flag);
    tcast_kernel<<<dim3(C_ / 32, C_ / 32), blk, 0, stream>>>(w_proj, wpT, C_, C_, flag);

    // down = x @ w_down -> bf16 [4096,1088]
    mfma_gemm<u16><<<dim3((DOWN_N + 127) / 128, NT_ / 128), blk, 0, stream>>>(
        xbf, C_, wdT, C_, downb, DOWN_N, NT_, DOWN_N, C_);
    // gates (VALU f32)
    gates_gemm<<<dim3(2, NT_ / 64), blk, 0, stream>>>(
        x, C_, w_gate, G_N, gates, G_N, NT_, G_N, C_, flag);
    // kv = c_kv @ w_ukv -> bf16 [4096,3072]
    mfma_gemm<u16><<<dim3(KV_N / 128, NT_ / 128), blk, 0, stream>>>(
        downb, DOWN_N, wukvT, 512, kvb, KV_N, NT_, KV_N, 512);
    // q_raw = c_q @ w_uq -> bf16 [4096,2048]
    mfma_gemm<u16><<<dim3(Q_N / 128, NT_ / 128), blk, 0, stream>>>(
        downb + 512, DOWN_N, wuqT, 512, qraw, Q_N, NT_, Q_N, 512);
    // assemble q/k/v
    assemble_kernel<<<dim3(NT_), blk, 0, stream>>>(
        downb, qraw, kvb, gates, ve, cosg, sing, qn, kn, vn, flag);
    // v transpose to [(b,h)][d][t]
    vtrans_kernel<<<dim3(T_ / 64, 2, B_ * H_), blk, 0, stream>>>(vn, vtb);
    // flash attention -> y bf16
    attn_mfma<<<dim3(T_ / 64, H_, B_), blk, 0, stream>>>(qn, kn, vtb, ybf, wsz);
    // out = y @ w_proj -> f32
    mfma_gemm<float><<<dim3(Q_N / 128, NT_ / 128), blk, 0, stream>>>(
        ybf, Q_N, wpT, C_, out, C_, NT_, C_, Q_N);
}

// Round 5
// 697.428 us; speedup vs baseline: 5.5501x; 1.4030x over previous
//
#include <hip/hip_runtime.h>

typedef unsigned short u16;
typedef __bf16 bfv8 __attribute__((ext_vector_type(8)));
typedef float f32x4 __attribute__((ext_vector_type(4)));
typedef u16 u16x8 __attribute__((ext_vector_type(8)));

#define B_      2
#define T_      2048
#define C_      2048
#define H_      16
#define HD_     128
#define NT_     (B_ * T_)
#define DOWN_N  1088
#define DCAT    1168   // 1088 (down) + 80 (gate logits)
#define KV_N    3072
#define Q_N     2048
#define EPS_    1.1920929e-07f
// softmax scale (1/sqrt(128)) * log2(e), for exp2-domain online softmax
#define CEXP    0.12751879524580262f

__device__ __forceinline__ float b2f(u16 u) {
    union { unsigned u; float f; } c; c.u = ((unsigned)u) << 16; return c.f;
}
__device__ __forceinline__ u16 f2b(float f) {
    union { float f; unsigned u; } c; c.f = f;
    return (u16)((c.u + 0x7FFFu + ((c.u >> 16) & 1u)) >> 16);
}
__device__ __forceinline__ float dynload(const void* p, size_t i, int bf) {
    if (bf) return b2f(((const u16*)p)[i]);
    return ((const float*)p)[i];
}

// ---------------------------------------------------------------------------
// Input dtype detector (writes flag[0] = 1 if bf16).
// ---------------------------------------------------------------------------
__global__ void detect_kernel(const unsigned* __restrict__ x, int* __restrict__ flag) {
    __shared__ int cnt;
    if (threadIdx.x == 0) cnt = 0;
    __syncthreads();
    int c = 0;
    for (int i = threadIdx.x; i < 4096; i += 256) {
        const unsigned w = x[i];
        const unsigned e = (w >> 7) & 0xFF;
        if (e >= 105 && e <= 140) ++c;
    }
    atomicAdd(&cnt, c);
    __syncthreads();
    if (threadIdx.x == 0) flag[0] = (cnt > 2300) ? 1 : 0;
}

// ---------------------------------------------------------------------------
// Elementwise cast (dyn f32/bf16 -> bf16), 8 elems/thread.
// ---------------------------------------------------------------------------
__global__ __launch_bounds__(256) void cast_kernel(
    const void* __restrict__ in, u16* __restrict__ out, int n, const int* __restrict__ flagp)
{
    const int fl = flagp[0];
    const int i0 = (blockIdx.x * 256 + threadIdx.x) * 8;
    if (i0 + 8 > n) return;
    u16x8 o;
    #pragma unroll
    for (int i = 0; i < 8; ++i) o[i] = f2b(dynload(in, (size_t)i0 + i, fl));
    *(u16x8*)(out + i0) = o;
}

// ---------------------------------------------------------------------------
// Transpose + cast: W[K][N] (dyn) -> W_T[N][K] (bf16). 32x32 LDS tiles.
// N may be non-multiple of 32 (w_gate N=80).
// ---------------------------------------------------------------------------
__global__ __launch_bounds__(256) void tcast_kernel(
    const void* __restrict__ in, u16* __restrict__ out, int K, int N, const int* __restrict__ flagp)
{
    const int fl = flagp[0];
    __shared__ float sf[32][33];
    const int n0 = blockIdx.x * 32, k0 = blockIdx.y * 32;
    const int tx = threadIdx.x & 31, ty = threadIdx.x >> 5;
    const int cr = (n0 + tx < N) ? (n0 + tx) : (N - 1);   // clamped read col
    #pragma unroll
    for (int i = 0; i < 4; ++i)
        sf[ty + 8 * i][tx] = dynload(in, (size_t)(k0 + ty + 8 * i) * N + cr, fl);
    __syncthreads();
    #pragma unroll
    for (int i = 0; i < 4; ++i) {
        const int n = n0 + ty + 8 * i;
        if (n < N) out[(size_t)n * K + k0 + tx] = f2b(sf[tx][ty + 8 * i]);
    }
}

// ---------------------------------------------------------------------------
// MFMA GEMM: C[M,N] = A[M,K] @ B[K,N], A row-major bf16, BT = B^T row-major
// bf16 [N][K]. 128x128 tile, BK=32, 4 waves each 64x64 (4x4 of 16x16x32).
// ---------------------------------------------------------------------------
__device__ __forceinline__ void stc(u16* p, float v)  { *p = f2b(v); }
__device__ __forceinline__ void stc(float* p, float v){ *p = v; }

template <typename TC>
__global__ __launch_bounds__(256) void mfma_gemm(
    const u16* __restrict__ A, int lda,
    const u16* __restrict__ BT, int ldb,
    TC* __restrict__ Cm, int ldc,
    int M, int N, int K)
{
    __shared__ u16 As[128][40];   // [m][k]
    __shared__ u16 Bs[128][40];   // [n][k]
    const int tid = threadIdx.x;
    const int m0 = blockIdx.y * 128, n0 = blockIdx.x * 128;
    const int w = tid >> 6, l = tid & 63;
    const int wm = (w >> 1) * 64, wn = (w & 1) * 64;
    const int lr = l & 15, lq = l >> 4;
    const int sr = tid >> 1, sh = (tid & 1) * 16;

    f32x4 acc[4][4];
    #pragma unroll
    for (int i = 0; i < 4; ++i)
        #pragma unroll
        for (int j = 0; j < 4; ++j) acc[i][j] = (f32x4){0.f, 0.f, 0.f, 0.f};

    const bool bvalid = (n0 + sr) < N;
    const u16* arow = A + (size_t)(m0 + sr) * lda + sh;
    const u16* brow = BT + (size_t)(bvalid ? (n0 + sr) : 0) * ldb + sh;

    for (int k0 = 0; k0 < K; k0 += 32) {
        u16x8 a0 = *(const u16x8*)(arow + k0);
        u16x8 a1 = *(const u16x8*)(arow + k0 + 8);
        u16x8 b0 = {0,0,0,0,0,0,0,0}, b1 = {0,0,0,0,0,0,0,0};
        if (bvalid) { b0 = *(const u16x8*)(brow + k0); b1 = *(const u16x8*)(brow + k0 + 8); }
        *(u16x8*)&As[sr][sh]     = a0;
        *(u16x8*)&As[sr][sh + 8] = a1;
        *(u16x8*)&Bs[sr][sh]     = b0;
        *(u16x8*)&Bs[sr][sh + 8] = b1;
        __syncthreads();
        bfv8 af[4], bf[4];
        #pragma unroll
        for (int mi = 0; mi < 4; ++mi) af[mi] = *(const bfv8*)&As[wm + mi * 16 + lr][lq * 8];
        #pragma unroll
        for (int ni = 0; ni < 4; ++ni) bf[ni] = *(const bfv8*)&Bs[wn + ni * 16 + lr][lq * 8];
        #pragma unroll
        for (int mi = 0; mi < 4; ++mi)
            #pragma unroll
            for (int ni = 0; ni < 4; ++ni)
                acc[mi][ni] = __builtin_amdgcn_mfma_f32_16x16x32_bf16(af[mi], bf[ni], acc[mi][ni], 0, 0, 0);
        __syncthreads();
    }

    #pragma unroll
    for (int mi = 0; mi < 4; ++mi) {
        #pragma unroll
        for (int ni = 0; ni < 4; ++ni) {
            const int col = n0 + wn + ni * 16 + lr;
            if (col < N) {
                #pragma unroll
                for (int r = 0; r < 4; ++r) {
                    const int row = m0 + wm + mi * 16 + lq * 4 + r;
                    stc(&Cm[(size_t)row * ldc + col], acc[mi][ni][r]);
                }
            }
        }
    }
}

// ---------------------------------------------------------------------------
// Assemble q/k/v per (b,t): rope + rmsnorm for q,k; gated v with ve einsum.
// Gate logits come from down cols 1088..1167 (fused into down GEMM).
// ---------------------------------------------------------------------------
__global__ __launch_bounds__(256) void assemble_kernel(
    const u16* __restrict__ down,      // [NT,1168] bf16
    const u16* __restrict__ qraw,      // [NT,2048] bf16
    const u16* __restrict__ kv,        // [NT,3072] bf16
    const void* __restrict__ ve,       // [NT,8192] dyn
    const void* __restrict__ cosg,     // [NT,32]   dyn
    const void* __restrict__ sing,     // [NT,32]   dyn
    u16* __restrict__ qo, u16* __restrict__ ko, u16* __restrict__ vo,
    const int* __restrict__ flagp)
{
    const int fl = flagp[0];
    const int bt = blockIdx.x;
    const int tid = threadIdx.x;
    __shared__ float cs[32], sn[32], kr[64];
    if (tid < 32) {
        cs[tid] = dynload(cosg, (size_t)bt * 32 + tid, fl);
        sn[tid] = dynload(sing, (size_t)bt * 32 + tid, fl);
    }
    __syncthreads();
    if (tid < 64) {
        const u16* rp = down + (size_t)bt * DCAT + 1024;
        const int d = tid;
        if (d < 32) kr[d] = b2f(rp[d]) * cs[d] + b2f(rp[d + 32]) * sn[d];
        else { const int r = d - 32; kr[d] = -b2f(rp[d - 32]) * sn[r] + b2f(rp[d]) * cs[r]; }
    }
    __syncthreads();

    const int h = tid >> 4;
    const int lane = tid & 15;
    const int d0 = lane * 8;

    // Q: rope on [64,128), rmsnorm over 128
    const u16* qr = qraw + (size_t)bt * Q_N + h * HD_;
    float vq[8];
    float ss = 0.f;
    #pragma unroll
    for (int i = 0; i < 8; ++i) {
        const int d = d0 + i;
        float xv = b2f(qr[d]);
        if (d >= 64) {
            if (d < 96) { const int r = d - 64; xv = xv * cs[r] + b2f(qr[d + 32]) * sn[r]; }
            else        { const int r = d - 96; xv = -b2f(qr[d - 32]) * sn[r] + xv * cs[r]; }
        }
        vq[i] = xv; ss += xv * xv;
    }
    #pragma unroll
    for (int off = 1; off < 16; off <<= 1) ss += __shfl_xor(ss, off);
    float rms = rsqrtf(ss * (1.f / 128.f) + EPS_);
    u16* qop = qo + (size_t)bt * Q_N + h * HD_ + d0;
    #pragma unroll
    for (int i = 0; i < 8; ++i) qop[i] = f2b(vq[i] * rms);

    // K: [k_nope(64) | roped k_rope(64)], rmsnorm over 128
    const u16* kvp = kv + (size_t)bt * KV_N + h * 192;
    float vk[8];
    ss = 0.f;
    #pragma unroll
    for (int i = 0; i < 8; ++i) {
        const int d = d0 + i;
        const float xv = (d < 64) ? b2f(kvp[d]) : kr[d - 64];
        vk[i] = xv; ss += xv * xv;
    }
    #pragma unroll
    for (int off = 1; off < 16; off <<= 1) ss += __shfl_xor(ss, off);
    rms = rsqrtf(ss * (1.f / 128.f) + EPS_);
    u16* kop = ko + (size_t)bt * Q_N + h * HD_ + d0;
    #pragma unroll
    for (int i = 0; i < 8; ++i) kop[i] = f2b(vk[i] * rms);

    // V: g0 * v + sum_m g[m+1] * ve[m]; gates = 2*sigmoid(down[1088 + h*5 + j])
    float g[5];
    #pragma unroll
    for (int j = 0; j < 5; ++j) {
        const float logit = b2f(down[(size_t)bt * DCAT + 1088 + h * 5 + j]);
        g[j] = 2.f / (1.f + expf(-logit));
    }
    const u16* vp = kvp + 64;
    const size_t vebase = (size_t)bt * 8192 + h * HD_;
    u16* vop = vo + (size_t)bt * Q_N + h * HD_ + d0;
    #pragma unroll
    for (int i = 0; i < 8; ++i) {
        const int d = d0 + i;
        float val = g[0] * b2f(vp[d]);
        #pragma unroll
        for (int m = 0; m < 4; ++m) val += g[1 + m] * dynload(ve, vebase + m * 2048 + d, fl);
        vop[i] = f2b(val);
    }
}

// ---------------------------------------------------------------------------
// V transpose: vn [b][t][h][d] -> vt [(b,h)][d][t]   (bf16, 64x64 tiles)
// ---------------------------------------------------------------------------
__global__ __launch_bounds__(256) void vtrans_kernel(
    const u16* __restrict__ vn, u16* __restrict__ vt)
{
    __shared__ u16 s[64][72];
    const int t0 = blockIdx.x * 64;
    const int d0 = blockIdx.y * 64;
    const int bh = blockIdx.z;
    const int tid = threadIdx.x;
    {
        const int tt = tid >> 2, seg = tid & 3;
        const u16* p = vn + ((size_t)((bh >> 4) * T_) + t0 + tt) * 2048 + (bh & 15) * 128 + d0 + seg * 16;
        u16x8 v0 = *(const u16x8*)(p);
        u16x8 v1 = *(const u16x8*)(p + 8);
        *(u16x8*)&s[tt][seg * 16]     = v0;
        *(u16x8*)&s[tt][seg * 16 + 8] = v1;
    }
    __syncthreads();
    {
        const int dd = tid >> 2, tseg = tid & 3;
        u16* q = vt + ((size_t)(bh * 128) + d0 + dd) * T_ + t0 + tseg * 16;
        #pragma unroll
        for (int g = 0; g < 2; ++g) {
            u16x8 o;
            #pragma unroll
            for (int i = 0; i < 8; ++i) o[i] = s[tseg * 16 + g * 8 + i][dd];
            *(u16x8*)(q + g * 8) = o;
        }
    }
}

// ---------------------------------------------------------------------------
// MFMA flash attention. Block = 512 threads (8 waves), 128 Q rows.
// 64-key tiles; each wave owns 16 Q rows. Online softmax in registers.
// LDS ~54 KB -> 2 blocks/CU (16 waves/CU).
// ---------------------------------------------------------------------------
__global__ __launch_bounds__(512) void attn_mfma(
    const u16* __restrict__ qn, const u16* __restrict__ kn,
    const u16* __restrict__ vt, u16* __restrict__ yb,
    const int* __restrict__ wptr)
{
    __shared__ u16 Ks[64][136];      // K tile row-major [key][d]
    __shared__ u16 VTs[128][72];     // V tile transposed [d][key]
    __shared__ u16 Ps[8][16][72];    // per-wave P round-trip [qrow][key]

    const int m0 = blockIdx.x * 128;
    const int h = blockIdx.y, b = blockIdx.z;
    const int W = wptr[0];
    const int tid = threadIdx.x;
    const int w = tid >> 6, l = tid & 63;
    const int lr = l & 15, lq = l >> 4;
    const int qr0 = m0 + w * 16;

    bfv8 qf[4];
    {
        const u16* qp = qn + ((size_t)(b * T_) + qr0 + lr) * 2048 + h * 128 + lq * 8;
        #pragma unroll
        for (int kk = 0; kk < 4; ++kk) qf[kk] = *(const bfv8*)(qp + kk * 32);
    }

    f32x4 oacc[8];
    #pragma unroll
    for (int i = 0; i < 8; ++i) oacc[i] = (f32x4){0.f, 0.f, 0.f, 0.f};
    float m_r[4] = {-1e30f, -1e30f, -1e30f, -1e30f};
    float l_r[4] = {0.f, 0.f, 0.f, 0.f};

    const int kkey = tid >> 3, kseg = tid & 7;   // K staging: 64 keys x 8 segs of 16
    const int vd = tid >> 2, vh = tid & 3;       // V staging: 128 d x 4 segs of 16

    int ns = m0 - W; if (ns < 0) ns = 0; ns &= ~63;
    const int ne = m0 + 64;                      // inclusive last tile start

    for (int n0 = ns; n0 <= ne; n0 += 64) {
        {   // stage K row-major
            const u16* kp = kn + ((size_t)(b * T_) + n0 + kkey) * 2048 + h * 128 + kseg * 16;
            u16x8 t0 = *(const u16x8*)(kp);
            u16x8 t1 = *(const u16x8*)(kp + 8);
            *(u16x8*)&Ks[kkey][kseg * 16]     = t0;
            *(u16x8*)&Ks[kkey][kseg * 16 + 8] = t1;
            // stage V^T
            const u16* vp = vt + ((size_t)(b * H_ + h) * 128 + vd) * T_ + n0 + vh * 16;
            u16x8 v0 = *(const u16x8*)(vp);
            u16x8 v1 = *(const u16x8*)(vp + 8);
            *(u16x8*)&VTs[vd][vh * 16]     = v0;
            *(u16x8*)&VTs[vd][vh * 16 + 8] = v1;
        }
        __syncthreads();

        // per-wave early-out on fully-masked tiles (barriers stay uniform)
        const bool active = (n0 <= qr0 + 15) && (n0 + 63 >= qr0 - W);
        if (active) {
            // S = Q K^T
            f32x4 s[4];
            #pragma unroll
            for (int f = 0; f < 4; ++f) {
                s[f] = (f32x4){0.f, 0.f, 0.f, 0.f};
                #pragma unroll
                for (int kk = 0; kk < 4; ++kk) {
                    bfv8 kf = *(const bfv8*)&Ks[f * 16 + lr][kk * 32 + lq * 8];
                    s[f] = __builtin_amdgcn_mfma_f32_16x16x32_bf16(qf[kk], kf, s[f], 0, 0, 0);
                }
            }

            if ((n0 + 63 > qr0) || (qr0 + 15 - n0 > W)) {
                #pragma unroll
                for (int f = 0; f < 4; ++f) {
                    const int si = n0 + f * 16 + lr;
                    #pragma unroll
                    for (int r = 0; r < 4; ++r) {
                        const int ti = qr0 + lq * 4 + r;
                        if (si > ti || ti - si > W) s[f][r] = -1e30f;
                    }
                }
            }

            // online softmax (rows in 16-lane groups)
            float al_r[4];
            #pragma unroll
            for (int r = 0; r < 4; ++r) {
                float mx = fmaxf(fmaxf(s[0][r], s[1][r]), fmaxf(s[2][r], s[3][r]));
                mx = fmaxf(mx, __shfl_xor(mx, 1));
                mx = fmaxf(mx, __shfl_xor(mx, 2));
                mx = fmaxf(mx, __shfl_xor(mx, 4));
                mx = fmaxf(mx, __shfl_xor(mx, 8));
                const float mnew = fmaxf(m_r[r], mx);
                al_r[r] = exp2f((m_r[r] - mnew) * CEXP);
                float ps = 0.f;
                #pragma unroll
                for (int f = 0; f < 4; ++f) {
                    const float sv = s[f][r];
                    const float pv = (sv <= -0.9e30f) ? 0.f : exp2f((sv - mnew) * CEXP);
                    s[f][r] = pv; ps += pv;
                }
                ps += __shfl_xor(ps, 1);
                ps += __shfl_xor(ps, 2);
                ps += __shfl_xor(ps, 4);
                ps += __shfl_xor(ps, 8);
                l_r[r] = l_r[r] * al_r[r] + ps;
                m_r[r] = mnew;
            }
            #pragma unroll
            for (int od = 0; od < 8; ++od)
                #pragma unroll
                for (int r = 0; r < 4; ++r) oacc[od][r] *= al_r[r];

            // P -> LDS (C-layout scatter); Ps[w] is wave-private, no barrier
            #pragma unroll
            for (int f = 0; f < 4; ++f)
                #pragma unroll
                for (int r = 0; r < 4; ++r)
                    Ps[w][lq * 4 + r][f * 16 + lr] = f2b(s[f][r]);

            // O += P V
            #pragma unroll
            for (int kk2 = 0; kk2 < 2; ++kk2) {
                bfv8 pf = *(const bfv8*)&Ps[w][lr][kk2 * 32 + lq * 8];
                #pragma unroll
                for (int od = 0; od < 8; ++od) {
                    bfv8 vf = *(const bfv8*)&VTs[od * 16 + lr][kk2 * 32 + lq * 8];
                    oacc[od] = __builtin_amdgcn_mfma_f32_16x16x32_bf16(pf, vf, oacc[od], 0, 0, 0);
                }
            }
        }
        __syncthreads();
    }

    float inv[4];
    #pragma unroll
    for (int r = 0; r < 4; ++r) inv[r] = 1.f / l_r[r];
    #pragma unroll
    for (int od = 0; od < 8; ++od)
        #pragma unroll
        for (int r = 0; r < 4; ++r) {
            const size_t idx = ((size_t)(b * T_) + qr0 + lq * 4 + r) * 2048 + h * 128 + od * 16 + lr;
            yb[idx] = f2b(oacc[od][r] * inv[r]);
        }
}

// ---------------------------------------------------------------------------
extern "C" void kernel_launch(void* const* d_in, const int* in_sizes, int n_in,
                              void* d_out, int out_size, void* d_ws, size_t ws_size,
                              hipStream_t stream)
{
    const void* x      = d_in[0];
    const void* ve     = d_in[1];
    const void* cosg   = d_in[2];
    const void* sing   = d_in[3];
    const void* w_down = d_in[4];
    const void* w_ukv  = d_in[5];
    const void* w_uq   = d_in[6];
    const void* w_gate = d_in[7];
    const void* w_proj = d_in[8];
    const int*  wsz    = (const int*)d_in[9];
    float* out = (float*)d_out;

    // workspace (~120 MB with aliasing)
    char* p = (char*)d_ws;
    u16* xbf    = (u16*)p; p += (size_t)NT_ * C_ * 2;          // reused as qn
    u16* wcatT  = (u16*)p; p += (size_t)DCAT * C_ * 2;         // [w_down|w_gate]^T
    u16* wukvT  = (u16*)p; p += (size_t)KV_N * 512 * 2;
    u16* wuqT   = (u16*)p; p += (size_t)Q_N * 512 * 2;
    u16* wpT    = (u16*)p; p += (size_t)C_ * C_ * 2;
    u16* downb  = (u16*)p; p += (size_t)NT_ * DCAT * 2;
    u16* kvb    = (u16*)p; p += (size_t)NT_ * KV_N * 2;
    u16* qraw   = (u16*)p; p += (size_t)NT_ * Q_N * 2;         // reused as vtb
    u16* kn     = (u16*)p; p += (size_t)NT_ * Q_N * 2;
    u16* vn     = (u16*)p; p += (size_t)NT_ * Q_N * 2;         // reused as ybf
    int* flag   = (int*)p; p += 256;
    u16* qn  = xbf;    // x_bf dead after down GEMM
    u16* vtb = qraw;   // qraw dead after assemble
    u16* ybf = vn;     // vn dead after vtrans (attn reads vtb)

    dim3 blk(256);
    detect_kernel<<<1, blk, 0, stream>>>((const unsigned*)x, flag);
    cast_kernel<<<dim3(NT_ * C_ / (256 * 8)), blk, 0, stream>>>(x, xbf, NT_ * C_, flag);
    tcast_kernel<<<dim3(DOWN_N / 32, C_ / 32), blk, 0, stream>>>(w_down, wcatT, C_, DOWN_N, flag);
    tcast_kernel<<<dim3(3, C_ / 32), blk, 0, stream>>>(w_gate, wcatT + (size_t)DOWN_N * C_, C_, 80, flag);
    tcast_kernel<<<dim3(KV_N / 32, 512 / 32), blk, 0, stream>>>(w_ukv, wukvT, 512, KV_N, flag);
    tcast_kernel<<<dim3(Q_N / 32, 512 / 32), blk, 0, stream>>>(w_uq, wuqT, 512, Q_N, flag);
    tcast_kernel<<<dim3(C_ / 32, C_ / 32), blk, 0, stream>>>(w_proj, wpT, C_, C_, flag);

    // down+gates = x @ [w_down|w_gate] -> bf16 [4096,1168]
    mfma_gemm<u16><<<dim3((DCAT + 127) / 128, NT_ / 128), blk, 0, stream>>>(
        xbf, C_, wcatT, C_, downb, DCAT, NT_, DCAT, C_);
    // kv = c_kv @ w_ukv -> bf16 [4096,3072]
    mfma_gemm<u16><<<dim3(KV_N / 128, NT_ / 128), blk, 0, stream>>>(
        downb, DCAT, wukvT, 512, kvb, KV_N, NT_, KV_N, 512);
    // q_raw = c_q @ w_uq -> bf16 [4096,2048]
    mfma_gemm<u16><<<dim3(Q_N / 128, NT_ / 128), blk, 0, stream>>>(
        downb + 512, DCAT, wuqT, 512, qraw, Q_N, NT_, Q_N, 512);
    // assemble q/k/v (incl. gate sigmoid from down logits)
    assemble_kernel<<<dim3(NT_), blk, 0, stream>>>(
        downb, qraw, kvb, ve, cosg, sing, qn, kn, vn, flag);
    // v transpose to [(b,h)][d][t]
    vtrans_kernel<<<dim3(T_ / 64, 2, B_ * H_), blk, 0, stream>>>(vn, vtb);
    // flash attention -> y bf16
    attn_mfma<<<dim3(T_ / 128, H_, B_), dim3(512), 0, stream>>>(qn, kn, vtb, ybf, wsz);
    // out = y @ w_proj -> f32
    mfma_gemm<float><<<dim3(Q_N / 128, NT_ / 128), blk, 0, stream>>>(
        ybf, Q_N, wpT, C_, out, C_, NT_, C_, Q_N);
}